// Round 1
// baseline (1563.680 us; speedup 1.0000x reference)
//
#include <hip/hip_runtime.h>

#define NPTS 294912
#define CDIM 128
#define HH 8
#define KPATCH 48
#define DD 16
#define NP (NPTS / KPATCH)      // 6144 patches
#define POS_BND 11
#define RPE_NUM 23
#define RPE_ROWS (3 * RPE_NUM)  // 69
#define QSCALE 0.25f

#define FS 132   // fo_l row stride (128 + 4 pad, keeps 16B align, breaks bank aliasing)
#define WS 68    // wT row stride (64 + 4 pad)

__global__ __launch_bounds__(256) void fused_patch_attn(
    const float* __restrict__ feat,
    const float* __restrict__ w_qkv,
    const float* __restrict__ b_qkv,
    const float* __restrict__ w_proj,
    const float* __restrict__ b_proj,
    const float* __restrict__ rpe,
    const int* __restrict__ order,
    const int* __restrict__ grid_coord,
    float* __restrict__ out)
{
    __shared__ int ord[KPATCH];
    __shared__ int gcl[KPATCH][3];
    __shared__ float rpe_l[RPE_ROWS * HH];
    __shared__ __align__(16) float q_l[HH][KPATCH][DD];
    __shared__ __align__(16) float k_l[HH][KPATCH][DD];
    __shared__ __align__(16) float v_l[HH][KPATCH][DD];
    __shared__ __align__(16) float fo_l[KPATCH][FS];   // feat tile, later attn-out tile
    __shared__ __align__(16) float wT[CDIM][WS];       // transposed weight chunk [k][col]

    const int p   = blockIdx.x;
    const int tid = threadIdx.x;
    const int tc  = tid & 15;   // col group
    const int tr  = tid >> 4;   // row group (0..15)

    if (tid < KPATCH) {
        int o = order[p * KPATCH + tid];
        ord[tid] = o;
        gcl[tid][0] = grid_coord[o * 3 + 0];
        gcl[tid][1] = grid_coord[o * 3 + 1];
        gcl[tid][2] = grid_coord[o * 3 + 2];
    }
    for (int e = tid; e < RPE_ROWS * HH; e += 256) rpe_l[e] = rpe[e];
    __syncthreads();

    // ---- gather feat rows (48 x 128) into fo_l ----
    for (int e = tid; e < KPATCH * (CDIM / 4); e += 256) {
        int r  = e >> 5;         // 32 float4 per row
        int c4 = e & 31;
        float4 vv = *((const float4*)(feat + (size_t)ord[r] * CDIM) + c4);
        *(float4*)&fo_l[r][c4 * 4] = vv;
    }

    // ---- QKV projection: 48 rows x 384 cols, K=128, 6 chunks of 64 cols ----
    for (int chunk = 0; chunk < 6; ++chunk) {
        __syncthreads();   // protect wT from previous readers / fo_l gather done
        for (int e = tid; e < 64 * CDIM; e += 256) {
            int j  = e >> 7;          // 0..63 col within chunk
            int kk = e & 127;         // k index
            wT[kk][j] = w_qkv[(chunk * 64 + j) * CDIM + kk];
        }
        __syncthreads();

        float acc[3][4] = {};
        for (int k4 = 0; k4 < CDIM / 4; ++k4) {
            float f0[4], f1[4], f2[4];
            *(float4*)f0 = *(const float4*)&fo_l[tr][k4 * 4];
            *(float4*)f1 = *(const float4*)&fo_l[tr + 16][k4 * 4];
            *(float4*)f2 = *(const float4*)&fo_l[tr + 32][k4 * 4];
            #pragma unroll
            for (int u = 0; u < 4; ++u) {
                float w[4];
                *(float4*)w = *(const float4*)&wT[k4 * 4 + u][tc * 4];
                #pragma unroll
                for (int j = 0; j < 4; ++j) {
                    acc[0][j] += f0[u] * w[j];
                    acc[1][j] += f1[u] * w[j];
                    acc[2][j] += f2[u] * w[j];
                }
            }
        }

        int which = chunk >> 1;   // uniform per chunk (64 | 128)
        #pragma unroll
        for (int i = 0; i < 3; ++i) {
            int r = tr + 16 * i;
            #pragma unroll
            for (int j = 0; j < 4; ++j) {
                int col = chunk * 64 + tc * 4 + j;
                float val = acc[i][j] + b_qkv[col];
                int h = (col >> 4) & 7;
                int d = col & 15;
                if (which == 0)      q_l[h][r][d] = val * QSCALE;
                else if (which == 1) k_l[h][r][d] = val;
                else                 v_l[h][r][d] = val;
            }
        }
    }
    __syncthreads();

    // ---- attention: one (h, q-row) pair per thread iteration ----
    for (int pp = tid; pp < HH * KPATCH; pp += 256) {
        int h  = pp / KPATCH;
        int kq = pp - h * KPATCH;
        float qv[DD];
        #pragma unroll
        for (int d4 = 0; d4 < DD / 4; ++d4)
            *(float4*)&qv[d4 * 4] = *(const float4*)&q_l[h][kq][d4 * 4];
        int gx = gcl[kq][0], gy = gcl[kq][1], gz = gcl[kq][2];

        float lo[KPATCH];
        float mx = -1e30f;
        #pragma unroll
        for (int m = 0; m < KPATCH; ++m) {
            float kv[DD];
            #pragma unroll
            for (int d4 = 0; d4 < DD / 4; ++d4)
                *(float4*)&kv[d4 * 4] = *(const float4*)&k_l[h][m][d4 * 4];
            float s = 0.f;
            #pragma unroll
            for (int d = 0; d < DD; ++d) s += qv[d] * kv[d];
            int rx = gx - gcl[m][0];
            int ry = gy - gcl[m][1];
            int rz = gz - gcl[m][2];
            rx = rx < -POS_BND ? -POS_BND : (rx > POS_BND ? POS_BND : rx);
            ry = ry < -POS_BND ? -POS_BND : (ry > POS_BND ? POS_BND : ry);
            rz = rz < -POS_BND ? -POS_BND : (rz > POS_BND ? POS_BND : rz);
            s += rpe_l[(rx + POS_BND) * HH + h]
               + rpe_l[(ry + POS_BND + RPE_NUM) * HH + h]
               + rpe_l[(rz + POS_BND + 2 * RPE_NUM) * HH + h];
            lo[m] = s;
            mx = fmaxf(mx, s);
        }

        float sum = 0.f;
        #pragma unroll
        for (int m = 0; m < KPATCH; ++m) {
            float e = __expf(lo[m] - mx);
            lo[m] = e;
            sum += e;
        }
        float inv = 1.0f / sum;

        float oacc[DD] = {};
        #pragma unroll
        for (int m = 0; m < KPATCH; ++m) {
            float pm = lo[m] * inv;
            float vv[DD];
            #pragma unroll
            for (int d4 = 0; d4 < DD / 4; ++d4)
                *(float4*)&vv[d4 * 4] = *(const float4*)&v_l[h][m][d4 * 4];
            #pragma unroll
            for (int d = 0; d < DD; ++d) oacc[d] += pm * vv[d];
        }
        #pragma unroll
        for (int d4 = 0; d4 < DD / 4; ++d4)
            *(float4*)&fo_l[kq][h * DD + d4 * 4] = *(const float4*)&oacc[d4 * 4];
    }

    // ---- output projection: 48 rows x 128 cols, 2 chunks of 64 ----
    for (int chunk = 0; chunk < 2; ++chunk) {
        __syncthreads();   // attn-out writes done; previous wT readers done
        for (int e = tid; e < 64 * CDIM; e += 256) {
            int j  = e >> 7;
            int kk = e & 127;
            wT[kk][j] = w_proj[(chunk * 64 + j) * CDIM + kk];
        }
        __syncthreads();

        float acc[3][4] = {};
        for (int k4 = 0; k4 < CDIM / 4; ++k4) {
            float f0[4], f1[4], f2[4];
            *(float4*)f0 = *(const float4*)&fo_l[tr][k4 * 4];
            *(float4*)f1 = *(const float4*)&fo_l[tr + 16][k4 * 4];
            *(float4*)f2 = *(const float4*)&fo_l[tr + 32][k4 * 4];
            #pragma unroll
            for (int u = 0; u < 4; ++u) {
                float w[4];
                *(float4*)w = *(const float4*)&wT[k4 * 4 + u][tc * 4];
                #pragma unroll
                for (int j = 0; j < 4; ++j) {
                    acc[0][j] += f0[u] * w[j];
                    acc[1][j] += f1[u] * w[j];
                    acc[2][j] += f2[u] * w[j];
                }
            }
        }

        #pragma unroll
        for (int i = 0; i < 3; ++i) {
            int r = tr + 16 * i;
            int col = chunk * 64 + tc * 4;
            float4 res;
            res.x = acc[i][0] + b_proj[col + 0];
            res.y = acc[i][1] + b_proj[col + 1];
            res.z = acc[i][2] + b_proj[col + 2];
            res.w = acc[i][3] + b_proj[col + 3];
            *(float4*)&out[(size_t)ord[r] * CDIM + col] = res;
        }
    }
}

extern "C" void kernel_launch(void* const* d_in, const int* in_sizes, int n_in,
                              void* d_out, int out_size, void* d_ws, size_t ws_size,
                              hipStream_t stream) {
    const float* feat   = (const float*)d_in[0];
    const float* w_qkv  = (const float*)d_in[1];
    const float* b_qkv  = (const float*)d_in[2];
    const float* w_proj = (const float*)d_in[3];
    const float* b_proj = (const float*)d_in[4];
    const float* rpe    = (const float*)d_in[5];
    const int*   order  = (const int*)d_in[6];
    // d_in[7] (inverse) not needed: ordered row i scatters to original row order[i]
    const int*   gc     = (const int*)d_in[8];
    float* out = (float*)d_out;

    fused_patch_attn<<<NP, 256, 0, stream>>>(feat, w_qkv, b_qkv, w_proj, b_proj,
                                             rpe, order, gc, out);
}

// Round 2
// 888.374 us; speedup vs baseline: 1.7602x; 1.7602x over previous
//
#include <hip/hip_runtime.h>

#define NPTS 294912
#define CDIM 128
#define HH 8
#define KPATCH 48
#define DD 16
#define NP (NPTS / KPATCH)      // 6144 patches
#define POS_BND 11
#define RPE_NUM 23
#define RPE_ROWS (3 * RPE_NUM)  // 69
#define QSCALE 0.25f

#define FS 132   // feat/attnout tile row stride (128 + 4)
#define WS 68    // wT row stride (64 + 4)

// LDS union layout (bytes):
//  Phase A (QKV GEMM):   fo_l[48][132] @ 0 (25344)  | wT[128][68] @ 25344 (34816)
//  Phase B (attention):  q @ 0, k @ 24576, v @ 49152   (each [8][48][16] = 24576)
//  Phase C (proj GEMM):  ao_l[48][132] @ 0 (25344)  | wTp[128][68] @ 25344 (34816)
#define UNI_BYTES 73728

__global__ __launch_bounds__(256, 2) void fused_patch_attn(
    const float* __restrict__ feat,
    const float* __restrict__ w_qkv,
    const float* __restrict__ b_qkv,
    const float* __restrict__ w_proj,
    const float* __restrict__ b_proj,
    const float* __restrict__ rpe,
    const int* __restrict__ order,
    const int* __restrict__ grid_coord,
    float* __restrict__ out)
{
    __shared__ int ord[KPATCH];
    __shared__ int gcl[KPATCH][3];
    __shared__ float rpe_l[RPE_ROWS * HH];
    __shared__ __align__(16) char uni[UNI_BYTES];

    float* uf = (float*)uni;
    float (*fo_l)[FS] = (float (*)[FS])uni;
    float (*wT)[WS]   = (float (*)[WS])(uni + 25344);
    float* qb = uf;                 // [8][48][16]
    float* kb = uf + 6144;
    float* vb = uf + 12288;
    float (*ao_l)[FS] = (float (*)[FS])uni;
    float (*wTp)[WS]  = (float (*)[WS])(uni + 25344);

    const int p   = blockIdx.x;
    const int tid = threadIdx.x;
    const int tc  = tid & 15;        // col group 0..15
    const int tr  = tid >> 4;        // row group 0..15
    // staging lane decomposition (bank-conflict-free wT writes)
    const int kkl = tid & 15;
    const int j4  = (tid >> 4) & 3;
    const int wv  = tid >> 6;

    if (tid < KPATCH) {
        int o = order[p * KPATCH + tid];
        ord[tid] = o;
        gcl[tid][0] = grid_coord[o * 3 + 0];
        gcl[tid][1] = grid_coord[o * 3 + 1];
        gcl[tid][2] = grid_coord[o * 3 + 2];
    }
    for (int e = tid; e < RPE_ROWS * HH; e += 256) rpe_l[e] = rpe[e];
    __syncthreads();

    // ---- gather feat rows (48 x 128) into fo_l ----
    for (int e = tid; e < KPATCH * (CDIM / 4); e += 256) {
        int r  = e >> 5;
        int c4 = e & 31;
        float4 vv = *((const float4*)(feat + (size_t)ord[r] * CDIM) + c4);
        *(float4*)&fo_l[r][c4 * 4] = vv;
    }

    // ---- QKV projection: 48 rows x 384 cols, 6 chunks of 64 cols ----
    // Results stay in registers (static indexing via full unroll).
    float qkvr[6][3][4];
    #pragma unroll
    for (int chunk = 0; chunk < 6; ++chunk) {
        __syncthreads();   // previous wT readers done (and fo_l gather, via chunk 0 pair)
        const int c0 = chunk * 64;
        #pragma unroll
        for (int it = 0; it < 32; ++it) {
            int kko = (it & 1) * 4 + wv;   // 0..7
            int jo  = it >> 1;             // 0..15
            int kk  = kkl + 16 * kko;      // 0..127
            int j   = j4 + 4 * jo;         // 0..63
            wT[kk][j] = w_qkv[(size_t)(c0 + j) * CDIM + kk];
        }
        __syncthreads();

        float acc[3][4] = {};
        for (int k4 = 0; k4 < CDIM / 4; ++k4) {
            float f0[4], f1[4], f2[4];
            *(float4*)f0 = *(const float4*)&fo_l[tr][k4 * 4];
            *(float4*)f1 = *(const float4*)&fo_l[tr + 16][k4 * 4];
            *(float4*)f2 = *(const float4*)&fo_l[tr + 32][k4 * 4];
            #pragma unroll
            for (int u = 0; u < 4; ++u) {
                float w[4];
                *(float4*)w = *(const float4*)&wT[k4 * 4 + u][tc * 4];
                #pragma unroll
                for (int j = 0; j < 4; ++j) {
                    acc[0][j] += f0[u] * w[j];
                    acc[1][j] += f1[u] * w[j];
                    acc[2][j] += f2[u] * w[j];
                }
            }
        }
        #pragma unroll
        for (int i = 0; i < 3; ++i)
            #pragma unroll
            for (int j = 0; j < 4; ++j)
                qkvr[chunk][i][j] = acc[i][j];
    }

    __syncthreads();   // all phase-A LDS reads done; region becomes q/k/v

    // ---- write deferred QKV registers into q/k/v LDS ----
    #pragma unroll
    for (int chunk = 0; chunk < 6; ++chunk) {
        const int col0 = chunk * 64 + tc * 4;
        const int h  = (col0 >> 4) & 7;
        const int d0 = col0 & 15;
        float* base = uf + (chunk >> 1) * 6144;   // q | k | v
        float4 bq = *(const float4*)&b_qkv[col0];
        #pragma unroll
        for (int i = 0; i < 3; ++i) {
            int r = tr + 16 * i;
            float4 val;
            val.x = qkvr[chunk][i][0] + bq.x;
            val.y = qkvr[chunk][i][1] + bq.y;
            val.z = qkvr[chunk][i][2] + bq.z;
            val.w = qkvr[chunk][i][3] + bq.w;
            if (chunk < 2) {
                val.x *= QSCALE; val.y *= QSCALE; val.z *= QSCALE; val.w *= QSCALE;
            }
            *(float4*)&base[(h * KPATCH + r) * DD + d0] = val;
        }
    }
    __syncthreads();

    // ---- attention: one (h, q-row) pair per thread slot, results deferred ----
    float oacc[2][DD];
    #pragma unroll
    for (int pi = 0; pi < 2; ++pi) {
        int pp = tid + pi * 256;
        if (pp < HH * KPATCH) {
            int h  = pp / KPATCH;
            int kq = pp - h * KPATCH;
            float qv[DD];
            #pragma unroll
            for (int d4 = 0; d4 < DD / 4; ++d4)
                *(float4*)&qv[d4 * 4] = *(const float4*)&qb[(h * KPATCH + kq) * DD + d4 * 4];
            int gx = gcl[kq][0], gy = gcl[kq][1], gz = gcl[kq][2];

            float lo[KPATCH];
            float mx = -1e30f;
            #pragma unroll
            for (int m = 0; m < KPATCH; ++m) {
                float kv[DD];
                #pragma unroll
                for (int d4 = 0; d4 < DD / 4; ++d4)
                    *(float4*)&kv[d4 * 4] = *(const float4*)&kb[(h * KPATCH + m) * DD + d4 * 4];
                float s = 0.f;
                #pragma unroll
                for (int d = 0; d < DD; ++d) s += qv[d] * kv[d];
                int rx = gx - gcl[m][0];
                int ry = gy - gcl[m][1];
                int rz = gz - gcl[m][2];
                rx = rx < -POS_BND ? -POS_BND : (rx > POS_BND ? POS_BND : rx);
                ry = ry < -POS_BND ? -POS_BND : (ry > POS_BND ? POS_BND : ry);
                rz = rz < -POS_BND ? -POS_BND : (rz > POS_BND ? POS_BND : rz);
                s += rpe_l[(rx + POS_BND) * HH + h]
                   + rpe_l[(ry + POS_BND + RPE_NUM) * HH + h]
                   + rpe_l[(rz + POS_BND + 2 * RPE_NUM) * HH + h];
                lo[m] = s;
                mx = fmaxf(mx, s);
            }

            float sum = 0.f;
            #pragma unroll
            for (int m = 0; m < KPATCH; ++m) {
                float e = __expf(lo[m] - mx);
                lo[m] = e;
                sum += e;
            }
            float inv = 1.0f / sum;

            #pragma unroll
            for (int d = 0; d < DD; ++d) oacc[pi][d] = 0.f;
            #pragma unroll
            for (int m = 0; m < KPATCH; ++m) {
                float pm = lo[m] * inv;
                float vv[DD];
                #pragma unroll
                for (int d4 = 0; d4 < DD / 4; ++d4)
                    *(float4*)&vv[d4 * 4] = *(const float4*)&vb[(h * KPATCH + m) * DD + d4 * 4];
                #pragma unroll
                for (int d = 0; d < DD; ++d) oacc[pi][d] += pm * vv[d];
            }
        }
    }
    __syncthreads();   // q/k/v reads done; region becomes ao_l | wTp

    // ---- write attention output tile (aliases q/k region) ----
    #pragma unroll
    for (int pi = 0; pi < 2; ++pi) {
        int pp = tid + pi * 256;
        if (pp < HH * KPATCH) {
            int h  = pp / KPATCH;
            int kq = pp - h * KPATCH;
            #pragma unroll
            for (int d4 = 0; d4 < DD / 4; ++d4)
                *(float4*)&ao_l[kq][h * DD + d4 * 4] = *(float4*)&oacc[pi][d4 * 4];
        }
    }

    // ---- output projection: 48 rows x 128 cols, 2 chunks of 64 ----
    #pragma unroll
    for (int pc = 0; pc < 2; ++pc) {
        if (pc > 0) __syncthreads();   // previous wTp readers done
        const int c0 = pc * 64;
        #pragma unroll
        for (int it = 0; it < 32; ++it) {
            int kko = (it & 1) * 4 + wv;
            int jo  = it >> 1;
            int kk  = kkl + 16 * kko;
            int j   = j4 + 4 * jo;
            wTp[kk][j] = w_proj[(size_t)(c0 + j) * CDIM + kk];
        }
        __syncthreads();   // staging done (pc0: also covers ao_l writes)

        float acc[3][4] = {};
        for (int k4 = 0; k4 < CDIM / 4; ++k4) {
            float f0[4], f1[4], f2[4];
            *(float4*)f0 = *(const float4*)&ao_l[tr][k4 * 4];
            *(float4*)f1 = *(const float4*)&ao_l[tr + 16][k4 * 4];
            *(float4*)f2 = *(const float4*)&ao_l[tr + 32][k4 * 4];
            #pragma unroll
            for (int u = 0; u < 4; ++u) {
                float w[4];
                *(float4*)w = *(const float4*)&wTp[k4 * 4 + u][tc * 4];
                #pragma unroll
                for (int j = 0; j < 4; ++j) {
                    acc[0][j] += f0[u] * w[j];
                    acc[1][j] += f1[u] * w[j];
                    acc[2][j] += f2[u] * w[j];
                }
            }
        }

        const int col0 = c0 + tc * 4;
        float4 bp = *(const float4*)&b_proj[col0];
        #pragma unroll
        for (int i = 0; i < 3; ++i) {
            int r = tr + 16 * i;
            float4 res;
            res.x = acc[i][0] + bp.x;
            res.y = acc[i][1] + bp.y;
            res.z = acc[i][2] + bp.z;
            res.w = acc[i][3] + bp.w;
            *(float4*)&out[(size_t)ord[r] * CDIM + col0] = res;
        }
    }
}

extern "C" void kernel_launch(void* const* d_in, const int* in_sizes, int n_in,
                              void* d_out, int out_size, void* d_ws, size_t ws_size,
                              hipStream_t stream) {
    const float* feat   = (const float*)d_in[0];
    const float* w_qkv  = (const float*)d_in[1];
    const float* b_qkv  = (const float*)d_in[2];
    const float* w_proj = (const float*)d_in[3];
    const float* b_proj = (const float*)d_in[4];
    const float* rpe    = (const float*)d_in[5];
    const int*   order  = (const int*)d_in[6];
    const int*   gc     = (const int*)d_in[8];
    float* out = (float*)d_out;

    fused_patch_attn<<<NP, 256, 0, stream>>>(feat, w_qkv, b_qkv, w_proj, b_proj,
                                             rpe, order, gc, out);
}

// Round 3
// 533.766 us; speedup vs baseline: 2.9295x; 1.6644x over previous
//
#include <hip/hip_runtime.h>

#define NPTS 294912
#define CDIM 128
#define HH 8
#define KPATCH 48
#define DD 16
#define NP (NPTS / KPATCH)      // 6144 patches
#define POS_BND 11
#define RPE_NUM 23
#define RPE_ROWS (3 * RPE_NUM)  // 69
#define QSCALE 0.25f

typedef __attribute__((ext_vector_type(8))) short short8v;  // 8 bf16
typedef __attribute__((ext_vector_type(4))) float f32x4;

// LDS union (73728 B):
//  Phase A (QKV GEMM):  featH [48][128]bf16 @0 (12288) | featL @12288 (12288)
//  Phase B (attention): q fp32 @0, k @24576, v @49152 (each [8][48][16] = 24576)
//  Phase C (proj GEMM): aoH @0 | aoL @12288   (attn-out hi/lo bf16 [48][128])
#define UNI_BYTES 73728

__device__ __forceinline__ void split8(const float* x, short8v& hi, short8v& lo) {
    #pragma unroll
    for (int i = 0; i < 8; ++i) {
        unsigned u = __float_as_uint(x[i]);
        hi[i] = (short)(u >> 16);                       // truncated bf16 (exact fp32 value)
        float l = x[i] - __uint_as_float(u & 0xffff0000u);  // exact residual
        lo[i] = (short)(__float_as_uint(l) >> 16);
    }
}

__global__ __launch_bounds__(256, 2) void fused_patch_attn(
    const float* __restrict__ feat,
    const float* __restrict__ w_qkv,
    const float* __restrict__ b_qkv,
    const float* __restrict__ w_proj,
    const float* __restrict__ b_proj,
    const float* __restrict__ rpe,
    const int* __restrict__ order,
    const int* __restrict__ grid_coord,
    float* __restrict__ out)
{
    __shared__ int ord[KPATCH];
    __shared__ int gcl[KPATCH][3];
    __shared__ float rpe_l[RPE_ROWS * HH];
    __shared__ __align__(16) char uni[UNI_BYTES];

    float* uf = (float*)uni;
    float* qb = uf;                 // [8][48][16] fp32
    float* kb = uf + 6144;
    float* vb = uf + 12288;

    const int p    = blockIdx.x;
    const int tid  = threadIdx.x;
    const int wid  = tid >> 6;
    const int lane = tid & 63;
    const int lrow = lane & 15;     // fragment row/col lane index
    const int lgrp = lane >> 4;     // k-group 0..3

    if (tid < KPATCH) {
        int o = order[p * KPATCH + tid];
        ord[tid] = o;
        gcl[tid][0] = grid_coord[o * 3 + 0];
        gcl[tid][1] = grid_coord[o * 3 + 1];
        gcl[tid][2] = grid_coord[o * 3 + 2];
    }
    for (int e = tid; e < RPE_ROWS * HH; e += 256) rpe_l[e] = rpe[e];
    __syncthreads();

    // ---- gather feat rows (48 x 128) -> bf16 hi/lo tiles (XOR-swizzled) ----
    for (int e = tid; e < KPATCH * 16; e += 256) {
        int r  = e >> 4;
        int c8 = e & 15;              // 8-float chunk
        const float* src = feat + (size_t)ord[r] * CDIM + c8 * 8;
        float x[8];
        *(float4*)(x)     = *(const float4*)src;
        *(float4*)(x + 4) = *(const float4*)(src + 4);
        short8v hi, lo;
        split8(x, hi, lo);
        int addr = (r * 256 + c8 * 16) ^ ((r & 7) << 4);
        *(short8v*)(uni + addr)         = hi;
        *(short8v*)(uni + 12288 + addr) = lo;
    }
    __syncthreads();

    // ---- QKV GEMM via split-bf16 MFMA: M=48 (3 mt), N=384 (6 nt/wave), K=128 ----
    f32x4 acc[3][6];
    #pragma unroll
    for (int i = 0; i < 3; ++i)
        #pragma unroll
        for (int j = 0; j < 6; ++j) acc[i][j] = (f32x4)0.0f;

    #pragma unroll
    for (int ks = 0; ks < 4; ++ks) {
        short8v aH[3], aL[3];
        #pragma unroll
        for (int mt = 0; mt < 3; ++mt) {
            int row  = mt * 16 + lrow;
            int boff = (row * 256 + ks * 64 + lgrp * 16) ^ ((row & 7) << 4);
            aH[mt] = *(const short8v*)(uni + boff);
            aL[mt] = *(const short8v*)(uni + 12288 + boff);
        }
        #pragma unroll
        for (int nt = 0; nt < 6; ++nt) {
            int NT = wid * 6 + nt;
            const float* wp = w_qkv + (size_t)(NT * 16 + lrow) * CDIM + ks * 32 + lgrp * 8;
            float x[8];
            *(float4*)(x)     = *(const float4*)wp;
            *(float4*)(x + 4) = *(const float4*)(wp + 4);
            short8v bH, bL;
            split8(x, bH, bL);
            #pragma unroll
            for (int mt = 0; mt < 3; ++mt) {
                acc[mt][nt] = __builtin_amdgcn_mfma_f32_16x16x32_bf16(aH[mt], bH, acc[mt][nt], 0, 0, 0);
                acc[mt][nt] = __builtin_amdgcn_mfma_f32_16x16x32_bf16(aL[mt], bH, acc[mt][nt], 0, 0, 0);
                acc[mt][nt] = __builtin_amdgcn_mfma_f32_16x16x32_bf16(aH[mt], bL, acc[mt][nt], 0, 0, 0);
            }
        }
    }
    __syncthreads();   // feat tile reads done; region becomes q/k/v

    // ---- write qkv accumulators (+bias, q*scale) into q/k/v fp32 LDS ----
    #pragma unroll
    for (int nt = 0; nt < 6; ++nt) {
        int NT   = wid * 6 + nt;
        int type = NT >> 3;          // 0=q 1=k 2=v (uniform per tile)
        int hh   = NT & 7;
        float bq = b_qkv[NT * 16 + lrow];
        float scale = (type == 0) ? QSCALE : 1.0f;
        float* base = uf + type * 6144 + (hh * KPATCH) * DD + lrow;
        #pragma unroll
        for (int mt = 0; mt < 3; ++mt)
            #pragma unroll
            for (int r = 0; r < 4; ++r) {
                int row = mt * 16 + lgrp * 4 + r;
                base[row * DD] = (acc[mt][nt][r] + bq) * scale;
            }
    }
    __syncthreads();

    // ---- attention (unchanged from round 2): one (h, q-row) per thread slot ----
    float oacc[2][DD];
    #pragma unroll
    for (int pi = 0; pi < 2; ++pi) {
        int pp = tid + pi * 256;
        if (pp < HH * KPATCH) {
            int h  = pp / KPATCH;
            int kq = pp - h * KPATCH;
            float qv[DD];
            #pragma unroll
            for (int d4 = 0; d4 < DD / 4; ++d4)
                *(float4*)&qv[d4 * 4] = *(const float4*)&qb[(h * KPATCH + kq) * DD + d4 * 4];
            int gx = gcl[kq][0], gy = gcl[kq][1], gz = gcl[kq][2];

            float lo[KPATCH];
            float mx = -1e30f;
            #pragma unroll
            for (int m = 0; m < KPATCH; ++m) {
                float kv[DD];
                #pragma unroll
                for (int d4 = 0; d4 < DD / 4; ++d4)
                    *(float4*)&kv[d4 * 4] = *(const float4*)&kb[(h * KPATCH + m) * DD + d4 * 4];
                float s = 0.f;
                #pragma unroll
                for (int d = 0; d < DD; ++d) s += qv[d] * kv[d];
                int rx = gx - gcl[m][0];
                int ry = gy - gcl[m][1];
                int rz = gz - gcl[m][2];
                rx = rx < -POS_BND ? -POS_BND : (rx > POS_BND ? POS_BND : rx);
                ry = ry < -POS_BND ? -POS_BND : (ry > POS_BND ? POS_BND : ry);
                rz = rz < -POS_BND ? -POS_BND : (rz > POS_BND ? POS_BND : rz);
                s += rpe_l[(rx + POS_BND) * HH + h]
                   + rpe_l[(ry + POS_BND + RPE_NUM) * HH + h]
                   + rpe_l[(rz + POS_BND + 2 * RPE_NUM) * HH + h];
                lo[m] = s;
                mx = fmaxf(mx, s);
            }

            float sum = 0.f;
            #pragma unroll
            for (int m = 0; m < KPATCH; ++m) {
                float e = __expf(lo[m] - mx);
                lo[m] = e;
                sum += e;
            }
            float inv = 1.0f / sum;

            #pragma unroll
            for (int d = 0; d < DD; ++d) oacc[pi][d] = 0.f;
            #pragma unroll
            for (int m = 0; m < KPATCH; ++m) {
                float pm = lo[m] * inv;
                float vv[DD];
                #pragma unroll
                for (int d4 = 0; d4 < DD / 4; ++d4)
                    *(float4*)&vv[d4 * 4] = *(const float4*)&vb[(h * KPATCH + m) * DD + d4 * 4];
                #pragma unroll
                for (int d = 0; d < DD; ++d) oacc[pi][d] += pm * vv[d];
            }
        }
    }
    __syncthreads();   // q/k/v reads done; region becomes aoH/aoL

    // ---- write attention output as bf16 hi/lo tile (swizzled like feat) ----
    #pragma unroll
    for (int pi = 0; pi < 2; ++pi) {
        int pp = tid + pi * 256;
        if (pp < HH * KPATCH) {
            int h  = pp / KPATCH;
            int kq = pp - h * KPATCH;
            short8v hi0, lo0, hi1, lo1;
            split8(&oacc[pi][0], hi0, lo0);
            split8(&oacc[pi][8], hi1, lo1);
            int sw = (kq & 7) << 4;
            int b0 = (kq * 256 + h * 32) ^ sw;
            int b1 = (kq * 256 + h * 32 + 16) ^ sw;
            *(short8v*)(uni + b0)          = hi0;
            *(short8v*)(uni + b1)          = hi1;
            *(short8v*)(uni + 12288 + b0)  = lo0;
            *(short8v*)(uni + 12288 + b1)  = lo1;
        }
    }
    __syncthreads();

    // ---- proj GEMM via split-bf16 MFMA: M=48, N=128 (2 nt/wave), K=128 ----
    f32x4 pacc[3][2];
    #pragma unroll
    for (int i = 0; i < 3; ++i)
        #pragma unroll
        for (int j = 0; j < 2; ++j) pacc[i][j] = (f32x4)0.0f;

    #pragma unroll
    for (int ks = 0; ks < 4; ++ks) {
        short8v aH[3], aL[3];
        #pragma unroll
        for (int mt = 0; mt < 3; ++mt) {
            int row  = mt * 16 + lrow;
            int boff = (row * 256 + ks * 64 + lgrp * 16) ^ ((row & 7) << 4);
            aH[mt] = *(const short8v*)(uni + boff);
            aL[mt] = *(const short8v*)(uni + 12288 + boff);
        }
        #pragma unroll
        for (int nt = 0; nt < 2; ++nt) {
            int NT = wid * 2 + nt;
            const float* wp = w_proj + (size_t)(NT * 16 + lrow) * CDIM + ks * 32 + lgrp * 8;
            float x[8];
            *(float4*)(x)     = *(const float4*)wp;
            *(float4*)(x + 4) = *(const float4*)(wp + 4);
            short8v bH, bL;
            split8(x, bH, bL);
            #pragma unroll
            for (int mt = 0; mt < 3; ++mt) {
                pacc[mt][nt] = __builtin_amdgcn_mfma_f32_16x16x32_bf16(aH[mt], bH, pacc[mt][nt], 0, 0, 0);
                pacc[mt][nt] = __builtin_amdgcn_mfma_f32_16x16x32_bf16(aL[mt], bH, pacc[mt][nt], 0, 0, 0);
                pacc[mt][nt] = __builtin_amdgcn_mfma_f32_16x16x32_bf16(aH[mt], bL, pacc[mt][nt], 0, 0, 0);
            }
        }
    }

    // ---- scatter rows to out (+bias) ----
    #pragma unroll
    for (int nt = 0; nt < 2; ++nt) {
        int NT = wid * 2 + nt;
        int c  = NT * 16 + lrow;
        float bp = b_proj[c];
        #pragma unroll
        for (int mt = 0; mt < 3; ++mt)
            #pragma unroll
            for (int r = 0; r < 4; ++r) {
                int row = mt * 16 + lgrp * 4 + r;
                out[(size_t)ord[row] * CDIM + c] = pacc[mt][nt][r] + bp;
            }
    }
}

extern "C" void kernel_launch(void* const* d_in, const int* in_sizes, int n_in,
                              void* d_out, int out_size, void* d_ws, size_t ws_size,
                              hipStream_t stream) {
    const float* feat   = (const float*)d_in[0];
    const float* w_qkv  = (const float*)d_in[1];
    const float* b_qkv  = (const float*)d_in[2];
    const float* w_proj = (const float*)d_in[3];
    const float* b_proj = (const float*)d_in[4];
    const float* rpe    = (const float*)d_in[5];
    const int*   order  = (const int*)d_in[6];
    const int*   gc     = (const int*)d_in[8];
    float* out = (float*)d_out;

    fused_patch_attn<<<NP, 256, 0, stream>>>(feat, w_qkv, b_qkv, w_proj, b_proj,
                                             rpe, order, gc, out);
}